// Round 4
// baseline (368.008 us; speedup 1.0000x reference)
//
#include <hip/hip_runtime.h>
#include <stdint.h>

typedef __bf16 bf16x8 __attribute__((ext_vector_type(8)));
typedef float f32x4 __attribute__((ext_vector_type(4)));
typedef float f32x16 __attribute__((ext_vector_type(16)));
typedef unsigned short u16x8 __attribute__((ext_vector_type(8)));

__device__ __forceinline__ unsigned short f2bf(float f) {
  union { float f; uint32_t u; } v; v.f = f;
  uint32_t r = v.u + 0x7FFFu + ((v.u >> 16) & 1u);  // RNE
  return (unsigned short)(r >> 16);
}

__device__ __forceinline__ f32x4 mfma16(bf16x8 a, bf16x8 b, f32x4 c) {
  return __builtin_amdgcn_mfma_f32_16x16x32_bf16(a, b, c, 0, 0, 0);
}

__device__ __forceinline__ f32x16 mfma32(bf16x8 a, bf16x8 b, f32x16 c) {
  return __builtin_amdgcn_mfma_f32_32x32x16_bf16(a, b, c, 0, 0, 0);
}

__device__ __forceinline__ void gload_lds16(const unsigned short* g, unsigned short* l) {
  __builtin_amdgcn_global_load_lds(
      (const __attribute__((address_space(1))) void*)g,
      (__attribute__((address_space(3))) void*)l, 16, 0, 0);
}

// 0.125 (hd^-0.5) * log2(e): folded into Q so softmax runs in exp2 domain.
#define SCALEQ 0.18033688011112042f

// ---------------- x fp32 -> bf16 ----------------
__global__ __launch_bounds__(256) void convert_f32_bf16(const float* __restrict__ in,
                                                        unsigned short* __restrict__ outp) {
  int i = blockIdx.x * 256 + threadIdx.x;
  const float4* p = (const float4*)in + (size_t)i * 2;
  float4 a = p[0], b = p[1];
  u16x8 o;
  o[0] = f2bf(a.x); o[1] = f2bf(a.y); o[2] = f2bf(a.z); o[3] = f2bf(a.w);
  o[4] = f2bf(b.x); o[5] = f2bf(b.y); o[6] = f2bf(b.z); o[7] = f2bf(b.w);
  *(u16x8*)&outp[(size_t)i * 8] = o;
}

// ---------------- w [K][N] fp32 -> wT [N][K] bf16 ----------------
__global__ __launch_bounds__(256) void transpose_to_bf16(const float* __restrict__ w,
                                                         unsigned short* __restrict__ wT,
                                                         int K, int N) {
  __shared__ unsigned short tile[64][72];
  const int n0 = blockIdx.x * 64, k0 = blockIdx.y * 64;
  const int t = threadIdx.x;
  {
    const int r = t >> 4, c0 = (t & 15) * 4;
#pragma unroll
    for (int i = 0; i < 4; ++i) {
      int rr = r + i * 16;
      float4 v = *(const float4*)&w[(size_t)(k0 + rr) * N + n0 + c0];
      tile[c0 + 0][rr] = f2bf(v.x);
      tile[c0 + 1][rr] = f2bf(v.y);
      tile[c0 + 2][rr] = f2bf(v.z);
      tile[c0 + 3][rr] = f2bf(v.w);
    }
  }
  __syncthreads();
  {
    const int c = t >> 2, r0 = (t & 3) * 16;
    u16x8 o1, o2;
#pragma unroll
    for (int i = 0; i < 8; ++i) { o1[i] = tile[c][r0 + i]; o2[i] = tile[c][r0 + 8 + i]; }
    *(u16x8*)&wT[(size_t)(n0 + c) * K + k0 + r0] = o1;
    *(u16x8*)&wT[(size_t)(n0 + c) * K + k0 + r0 + 8] = o2;
  }
}

// ---------------- QKV GEMM: [8192,1024] x [1024,3072] + bias ----------------
__global__ __launch_bounds__(256) void qkv_gemm(const unsigned short* __restrict__ xbf,
                                                const unsigned short* __restrict__ wT,
                                                const float* __restrict__ bias,
                                                unsigned short* __restrict__ qb,
                                                unsigned short* __restrict__ kb,
                                                unsigned short* __restrict__ vtb) {
  __shared__ unsigned short As[128 * 32];
  __shared__ unsigned short Bs[128 * 32];
  const int tid = threadIdx.x, lane = tid & 63, wave = tid >> 6;
  const int mb = blockIdx.y * 128, nb = blockIdx.x * 128;
  const int wr = (wave >> 1) * 64, wc = (wave & 1) * 64;
  const int fr = lane & 15, fk = (lane >> 4) * 8;
  f32x4 acc[4][4] = {};
  for (int kt = 0; kt < 1024; kt += 32) {
    __syncthreads();
#pragma unroll
    for (int i = 0; i < 2; ++i) {
      int ch = wave * 128 + i * 64 + lane;
      int r = ch >> 2, ko = (ch & 3) * 8;
      gload_lds16(xbf + (size_t)(mb + r) * 1024 + kt + ko, &As[(wave * 128 + i * 64) * 8]);
      gload_lds16(wT + (size_t)(nb + r) * 1024 + kt + ko, &Bs[(wave * 128 + i * 64) * 8]);
    }
    __syncthreads();
    bf16x8 a[4], bq[4];
#pragma unroll
    for (int m = 0; m < 4; ++m) a[m] = *(const bf16x8*)&As[(wr + m * 16 + fr) * 32 + fk];
#pragma unroll
    for (int n = 0; n < 4; ++n) bq[n] = *(const bf16x8*)&Bs[(wc + n * 16 + fr) * 32 + fk];
#pragma unroll
    for (int m = 0; m < 4; ++m)
#pragma unroll
      for (int n = 0; n < 4; ++n) acc[m][n] = mfma16(a[m], bq[n], acc[m][n]);
  }
#pragma unroll
  for (int m = 0; m < 4; ++m)
#pragma unroll
    for (int n = 0; n < 4; ++n) {
      int col = nb + wc + n * 16 + fr;
      float bv = bias[col];
      int type = col >> 10, cc = col & 1023, h = cc >> 6, d = cc & 63;
#pragma unroll
      for (int j = 0; j < 4; ++j) {
        int row = mb + wr + m * 16 + (lane >> 4) * 4 + j;
        int bidx = row >> 11, s = row & 2047;
        float val = acc[m][n][j] + bv;
        if (type == 0)
          qb[(((size_t)(bidx * 16 + h)) * 2048 + s) * 64 + d] = f2bf(val * SCALEQ);
        else if (type == 1)
          kb[(((size_t)(bidx * 16 + h)) * 2048 + s) * 64 + d] = f2bf(val);
        else
          vtb[(((size_t)(bidx * 16 + h)) * 64 + d) * 2048 + s] = f2bf(val);
      }
    }
}

// ---------------- flash attention: 32x32 MFMA, in-register softmax ----------------
// Identical to round 3 EXCEPT all v_permlane32_swap asm replaced by verified
// primitives: __shfl_xor(.,32) for cross-half reduce, f2bf-pack + shfl_xor +
// per-lane selects for the P -> B-fragment transpose.
__global__ __launch_bounds__(256, 4) void attn_kernel(const unsigned short* __restrict__ qg,
                                                      const unsigned short* __restrict__ kgl,
                                                      const unsigned short* __restrict__ vtg,
                                                      unsigned short* __restrict__ attnb) {
  const int tid = threadIdx.x;
  const int lane = tid & 63;
  const int l31 = lane & 31, hl = lane >> 5;
  const int h8 = hl * 8;
  const int wave = tid >> 6;

  // XCD-locality remap: 8 bh per XCD (K+V of 8 bh = 4MB = one XCD L2)
  const int L = blockIdx.y * 16 + blockIdx.x;  // 0..1023
  const int xcd = L & 7, sl = L >> 3;
  const int bh = xcd * 8 + (sl & 7);
  const int qc = sl >> 3;  // 0..15
  const int b = bh >> 4, hh = bh & 15;

  const unsigned short* Qg = qg + (size_t)bh * 2048 * 64;
  const unsigned short* Kg = kgl + (size_t)bh * 2048 * 64;
  const unsigned short* Vg = vtg + (size_t)bh * 64 * 2048;
  const int q0 = qc * 128 + wave * 32;

  // persistent Q B-frags: col q = l31, d = dw*16 + h8 .. +7 (pre-scaled by 0.125*log2e)
  bf16x8 qf[4];
#pragma unroll
  for (int dw = 0; dw < 4; ++dw)
    qf[dw] = *(const bf16x8*)&Qg[(size_t)(q0 + l31) * 64 + dw * 16 + h8];

  f32x16 o0 = {}, o1 = {};
  float mrun = -1e30f, lrun = 0.f;

  for (int kbase = 0; kbase < 2048; kbase += 32) {
    // phase-lock the 4 waves of this block so their identical K/V loads hit L1
    __builtin_amdgcn_s_barrier();

    // K A-frags: row key = kbase + l31, d = dw*16 + h8
    const unsigned short* kr = &Kg[(size_t)(kbase + l31) * 64 + h8];
    bf16x8 k0 = *(const bf16x8*)&kr[0];
    bf16x8 k1 = *(const bf16x8*)&kr[16];
    bf16x8 k2 = *(const bf16x8*)&kr[32];
    bf16x8 k3 = *(const bf16x8*)&kr[48];
    // V^T A-frags (issued early; consumed after softmax)
    const unsigned short* vr0 = &Vg[(size_t)l31 * 2048 + kbase + h8];
    const unsigned short* vr1 = &Vg[(size_t)(32 + l31) * 2048 + kbase + h8];
    bf16x8 v00 = *(const bf16x8*)&vr0[0];
    bf16x8 v01 = *(const bf16x8*)&vr0[16];
    bf16x8 v10 = *(const bf16x8*)&vr1[0];
    bf16x8 v11 = *(const bf16x8*)&vr1[16];

    // S^T: 32 keys x 32 q, lane holds 16 key-values for q = l31
    // sa[r] = S[key = kbase + (r&3) + 8*(r>>2) + 4*hl][q = q0 + l31]
    f32x16 sa = {};
    sa = mfma32(k0, qf[0], sa);
    sa = mfma32(k1, qf[1], sa);
    sa = mfma32(k2, qf[2], sa);
    sa = mfma32(k3, qf[3], sa);

    // ---- online softmax, per-lane (q = l31) ----
    float ma = fmaxf(fmaxf(fmaxf(sa[0], sa[1]), fmaxf(sa[2], sa[3])),
                     fmaxf(fmaxf(sa[4], sa[5]), fmaxf(sa[6], sa[7])));
    float mb2 = fmaxf(fmaxf(fmaxf(sa[8], sa[9]), fmaxf(sa[10], sa[11])),
                      fmaxf(fmaxf(sa[12], sa[13]), fmaxf(sa[14], sa[15])));
    float mx = fmaxf(ma, mb2);
    mx = fmaxf(mx, __shfl_xor(mx, 32));  // cross-half (verified primitive)
    // T13 defer-rescale (exp2 domain, p <= 2^6)
    if (!__all(mx <= mrun + 6.0f)) {
      float nm = fmaxf(mrun, mx);
      float fs = __builtin_amdgcn_exp2f(mrun - nm);
      mrun = nm;
      lrun *= fs;
#pragma unroll
      for (int r = 0; r < 16; ++r) { o0[r] *= fs; o1[r] *= fs; }
    }
#pragma unroll
    for (int r = 0; r < 16; ++r) sa[r] = __builtin_amdgcn_exp2f(sa[r] - mrun);
    float r0s = ((sa[0] + sa[1]) + (sa[2] + sa[3])) + ((sa[4] + sa[5]) + (sa[6] + sa[7]));
    float r1s = ((sa[8] + sa[9]) + (sa[10] + sa[11])) + ((sa[12] + sa[13]) + (sa[14] + sa[15]));
    float rs = r0s + r1s;
    rs += __shfl_xor(rs, 32);  // cross-half
    lrun += rs;

    // ---- P -> PV B-frags: f2bf pack + shfl_xor(32) + per-lane select ----
    // pre-move: cN holds keys (4*hl + {0,1}) + 8*floor(N/2)... explicitly:
    //   c0=(0,1)/(4,5) c1=(2,3)/(6,7) c2=(8,9)/(12,13) c3=(10,11)/(14,15)  [hl0/hl1]
    //   c4..c7 same +16.
    uint32_t c0 = (uint32_t)f2bf(sa[0]) | ((uint32_t)f2bf(sa[1]) << 16);
    uint32_t c1 = (uint32_t)f2bf(sa[2]) | ((uint32_t)f2bf(sa[3]) << 16);
    uint32_t c2 = (uint32_t)f2bf(sa[4]) | ((uint32_t)f2bf(sa[5]) << 16);
    uint32_t c3 = (uint32_t)f2bf(sa[6]) | ((uint32_t)f2bf(sa[7]) << 16);
    uint32_t c4 = (uint32_t)f2bf(sa[8]) | ((uint32_t)f2bf(sa[9]) << 16);
    uint32_t c5 = (uint32_t)f2bf(sa[10]) | ((uint32_t)f2bf(sa[11]) << 16);
    uint32_t c6 = (uint32_t)f2bf(sa[12]) | ((uint32_t)f2bf(sa[13]) << 16);
    uint32_t c7 = (uint32_t)f2bf(sa[14]) | ((uint32_t)f2bf(sa[15]) << 16);
    uint32_t x0 = (uint32_t)__shfl_xor((int)c0, 32);
    uint32_t x1 = (uint32_t)__shfl_xor((int)c1, 32);
    uint32_t x2 = (uint32_t)__shfl_xor((int)c2, 32);
    uint32_t x3 = (uint32_t)__shfl_xor((int)c3, 32);
    uint32_t x4 = (uint32_t)__shfl_xor((int)c4, 32);
    uint32_t x5 = (uint32_t)__shfl_xor((int)c5, 32);
    uint32_t x6 = (uint32_t)__shfl_xor((int)c6, 32);
    uint32_t x7 = (uint32_t)__shfl_xor((int)c7, 32);
    const bool h = (hl != 0);
    union PU { uint32_t u[4]; bf16x8 v; };
    PU p0, p1;
    // B-frag: lane element dwords must hold keys (hl*8 + {0,1},{2,3},{4,5},{6,7}) per chunk
    p0.u[0] = h ? x2 : c0;  p0.u[1] = h ? x3 : c1;
    p0.u[2] = h ? c2 : x0;  p0.u[3] = h ? c3 : x1;   // chunk 0: keys 0..15
    p1.u[0] = h ? x6 : c4;  p1.u[1] = h ? x7 : c5;
    p1.u[2] = h ? c6 : x4;  p1.u[3] = h ? c7 : x5;   // chunk 1: keys 16..31

    // ---- O^T += V^T x P^T ----
    o0 = mfma32(v00, p0.v, o0);
    o0 = mfma32(v01, p1.v, o0);
    o1 = mfma32(v10, p0.v, o1);
    o1 = mfma32(v11, p1.v, o1);
  }

  // ---- epilogue: per-lane normalize (q = l31), store O^T -> [b][s][hh*64+d]
  float invl = 1.0f / lrun;
  const size_t base = ((size_t)(b * 2048 + q0 + l31)) * 1024 + hh * 64;
#pragma unroll
  for (int r = 0; r < 16; ++r) {
    int d = (r & 3) + 8 * (r >> 2) + 4 * hl;
    attnb[base + d] = f2bf(o0[r] * invl);
    attnb[base + 32 + d] = f2bf(o1[r] * invl);
  }
}

// ---------------- proj GEMM: attn[8192,1024] x [1024,1024] + bias -> fp32 out ----------------
__global__ __launch_bounds__(256) void proj_gemm(const unsigned short* __restrict__ abf,
                                                 const unsigned short* __restrict__ wT,
                                                 const float* __restrict__ bias,
                                                 float* __restrict__ outp) {
  __shared__ unsigned short As[128 * 32];
  __shared__ unsigned short Bs[128 * 32];
  const int tid = threadIdx.x, lane = tid & 63, wave = tid >> 6;
  const int mb = blockIdx.y * 128, nb = blockIdx.x * 128;
  const int wr = (wave >> 1) * 64, wc = (wave & 1) * 64;
  const int fr = lane & 15, fk = (lane >> 4) * 8;
  f32x4 acc[4][4] = {};
  for (int kt = 0; kt < 1024; kt += 32) {
    __syncthreads();
#pragma unroll
    for (int i = 0; i < 2; ++i) {
      int ch = wave * 128 + i * 64 + lane;
      int r = ch >> 2, ko = (ch & 3) * 8;
      gload_lds16(abf + (size_t)(mb + r) * 1024 + kt + ko, &As[(wave * 128 + i * 64) * 8]);
      gload_lds16(wT + (size_t)(nb + r) * 1024 + kt + ko, &Bs[(wave * 128 + i * 64) * 8]);
    }
    __syncthreads();
    bf16x8 a[4], bq[4];
#pragma unroll
    for (int m = 0; m < 4; ++m) a[m] = *(const bf16x8*)&As[(wr + m * 16 + fr) * 32 + fk];
#pragma unroll
    for (int n = 0; n < 4; ++n) bq[n] = *(const bf16x8*)&Bs[(wc + n * 16 + fr) * 32 + fk];
#pragma unroll
    for (int m = 0; m < 4; ++m)
#pragma unroll
      for (int n = 0; n < 4; ++n) acc[m][n] = mfma16(a[m], bq[n], acc[m][n]);
  }
#pragma unroll
  for (int m = 0; m < 4; ++m)
#pragma unroll
    for (int n = 0; n < 4; ++n) {
      int col = nb + wc + n * 16 + fr;
      float bv = bias[col];
#pragma unroll
      for (int j = 0; j < 4; ++j) {
        int row = mb + wr + m * 16 + (lane >> 4) * 4 + j;
        outp[(size_t)row * 1024 + col] = acc[m][n][j] + bv;
      }
    }
}

extern "C" void kernel_launch(void* const* d_in, const int* in_sizes, int n_in,
                              void* d_out, int out_size, void* d_ws, size_t ws_size,
                              hipStream_t stream) {
  const float* x = (const float*)d_in[0];
  const float* w_qkv = (const float*)d_in[1];
  const float* b_qkv = (const float*)d_in[2];
  const float* w_proj = (const float*)d_in[3];
  const float* b_proj = (const float*)d_in[4];
  float* outp = (float*)d_out;
  char* ws = (char*)d_ws;

  const size_t OFF_XBF = 0;                 // 16,777,216 (also reused as attn output)
  const size_t OFF_WTQKV = 16777216;        //  6,291,456
  const size_t OFF_WTPROJ = 23068672;       //  2,097,152
  const size_t OFF_Q = 25165824;            // 16,777,216
  const size_t OFF_K = 41943040;            // 16,777,216
  const size_t OFF_VT = 58720256;           // 16,777,216
  const size_t NEED = 75497472;
  if (ws_size < NEED) return;

  unsigned short* xbf = (unsigned short*)(ws + OFF_XBF);
  unsigned short* wTqkv = (unsigned short*)(ws + OFF_WTQKV);
  unsigned short* wTproj = (unsigned short*)(ws + OFF_WTPROJ);
  unsigned short* qbuf = (unsigned short*)(ws + OFF_Q);
  unsigned short* kbuf = (unsigned short*)(ws + OFF_K);
  unsigned short* vtbuf = (unsigned short*)(ws + OFF_VT);
  unsigned short* attnb = xbf;  // alias: xbf dead after qkv_gemm

  hipLaunchKernelGGL(convert_f32_bf16, dim3(4096), dim3(256), 0, stream, x, xbf);
  hipLaunchKernelGGL(transpose_to_bf16, dim3(48, 16), dim3(256), 0, stream, w_qkv, wTqkv, 1024, 3072);
  hipLaunchKernelGGL(transpose_to_bf16, dim3(16, 16), dim3(256), 0, stream, w_proj, wTproj, 1024, 1024);
  hipLaunchKernelGGL(qkv_gemm, dim3(24, 64), dim3(256), 0, stream, xbf, wTqkv, b_qkv, qbuf, kbuf, vtbuf);
  hipLaunchKernelGGL(attn_kernel, dim3(16, 64), dim3(256), 0, stream, qbuf, kbuf, vtbuf, attnb);
  hipLaunchKernelGGL(proj_gemm, dim3(8, 64), dim3(256), 0, stream, attnb, wTproj, b_proj, outp);
}

// Round 5
// 264.351 us; speedup vs baseline: 1.3921x; 1.3921x over previous
//
#include <hip/hip_runtime.h>
#include <stdint.h>

typedef __bf16 bf16x8 __attribute__((ext_vector_type(8)));
typedef float f32x4 __attribute__((ext_vector_type(4)));
typedef float f32x16 __attribute__((ext_vector_type(16)));
typedef unsigned short u16x8 __attribute__((ext_vector_type(8)));

__device__ __forceinline__ unsigned short f2bf(float f) {
  union { float f; uint32_t u; } v; v.f = f;
  uint32_t r = v.u + 0x7FFFu + ((v.u >> 16) & 1u);  // RNE
  return (unsigned short)(r >> 16);
}

__device__ __forceinline__ f32x4 mfma16(bf16x8 a, bf16x8 b, f32x4 c) {
  return __builtin_amdgcn_mfma_f32_16x16x32_bf16(a, b, c, 0, 0, 0);
}

__device__ __forceinline__ f32x16 mfma32(bf16x8 a, bf16x8 b, f32x16 c) {
  return __builtin_amdgcn_mfma_f32_32x32x16_bf16(a, b, c, 0, 0, 0);
}

// packed f32x2 -> bf16x2 (S0 -> low half). HW-verified recipe (learn_hip T12).
__device__ __forceinline__ uint32_t cvtpk(float lo, float hi) {
  uint32_t r;
  asm("v_cvt_pk_bf16_f32 %0, %1, %2" : "=v"(r) : "v"(lo), "v"(hi));
  return r;
}

__device__ __forceinline__ void gload_lds16(const unsigned short* g, unsigned short* l) {
  __builtin_amdgcn_global_load_lds(
      (const __attribute__((address_space(1))) void*)g,
      (__attribute__((address_space(3))) void*)l, 16, 0, 0);
}

// 0.125 (hd^-0.5) * log2(e): folded into Q so softmax runs in exp2 domain.
#define SCALEQ 0.18033688011112042f

// ---------------- x fp32 -> bf16 ----------------
__global__ __launch_bounds__(256) void convert_f32_bf16(const float* __restrict__ in,
                                                        unsigned short* __restrict__ outp) {
  int i = blockIdx.x * 256 + threadIdx.x;
  const float4* p = (const float4*)in + (size_t)i * 2;
  float4 a = p[0], b = p[1];
  u16x8 o;
  o[0] = f2bf(a.x); o[1] = f2bf(a.y); o[2] = f2bf(a.z); o[3] = f2bf(a.w);
  o[4] = f2bf(b.x); o[5] = f2bf(b.y); o[6] = f2bf(b.z); o[7] = f2bf(b.w);
  *(u16x8*)&outp[(size_t)i * 8] = o;
}

// ---------------- w [K][N] fp32 -> wT [N][K] bf16 ----------------
__global__ __launch_bounds__(256) void transpose_to_bf16(const float* __restrict__ w,
                                                         unsigned short* __restrict__ wT,
                                                         int K, int N) {
  __shared__ unsigned short tile[64][72];
  const int n0 = blockIdx.x * 64, k0 = blockIdx.y * 64;
  const int t = threadIdx.x;
  {
    const int r = t >> 4, c0 = (t & 15) * 4;
#pragma unroll
    for (int i = 0; i < 4; ++i) {
      int rr = r + i * 16;
      float4 v = *(const float4*)&w[(size_t)(k0 + rr) * N + n0 + c0];
      tile[c0 + 0][rr] = f2bf(v.x);
      tile[c0 + 1][rr] = f2bf(v.y);
      tile[c0 + 2][rr] = f2bf(v.z);
      tile[c0 + 3][rr] = f2bf(v.w);
    }
  }
  __syncthreads();
  {
    const int c = t >> 2, r0 = (t & 3) * 16;
    u16x8 o1, o2;
#pragma unroll
    for (int i = 0; i < 8; ++i) { o1[i] = tile[c][r0 + i]; o2[i] = tile[c][r0 + 8 + i]; }
    *(u16x8*)&wT[(size_t)(n0 + c) * K + k0 + r0] = o1;
    *(u16x8*)&wT[(size_t)(n0 + c) * K + k0 + r0 + 8] = o2;
  }
}

// ---------------- QKV GEMM: [8192,1024] x [1024,3072] + bias ----------------
__global__ __launch_bounds__(256) void qkv_gemm(const unsigned short* __restrict__ xbf,
                                                const unsigned short* __restrict__ wT,
                                                const float* __restrict__ bias,
                                                unsigned short* __restrict__ qb,
                                                unsigned short* __restrict__ kb,
                                                unsigned short* __restrict__ vtb) {
  __shared__ unsigned short As[128 * 32];
  __shared__ unsigned short Bs[128 * 32];
  const int tid = threadIdx.x, lane = tid & 63, wave = tid >> 6;
  const int mb = blockIdx.y * 128, nb = blockIdx.x * 128;
  const int wr = (wave >> 1) * 64, wc = (wave & 1) * 64;
  const int fr = lane & 15, fk = (lane >> 4) * 8;
  f32x4 acc[4][4] = {};
  for (int kt = 0; kt < 1024; kt += 32) {
    __syncthreads();
#pragma unroll
    for (int i = 0; i < 2; ++i) {
      int ch = wave * 128 + i * 64 + lane;
      int r = ch >> 2, ko = (ch & 3) * 8;
      gload_lds16(xbf + (size_t)(mb + r) * 1024 + kt + ko, &As[(wave * 128 + i * 64) * 8]);
      gload_lds16(wT + (size_t)(nb + r) * 1024 + kt + ko, &Bs[(wave * 128 + i * 64) * 8]);
    }
    __syncthreads();
    bf16x8 a[4], bq[4];
#pragma unroll
    for (int m = 0; m < 4; ++m) a[m] = *(const bf16x8*)&As[(wr + m * 16 + fr) * 32 + fk];
#pragma unroll
    for (int n = 0; n < 4; ++n) bq[n] = *(const bf16x8*)&Bs[(wc + n * 16 + fr) * 32 + fk];
#pragma unroll
    for (int m = 0; m < 4; ++m)
#pragma unroll
      for (int n = 0; n < 4; ++n) acc[m][n] = mfma16(a[m], bq[n], acc[m][n]);
  }
#pragma unroll
  for (int m = 0; m < 4; ++m)
#pragma unroll
    for (int n = 0; n < 4; ++n) {
      int col = nb + wc + n * 16 + fr;
      float bv = bias[col];
      int type = col >> 10, cc = col & 1023, h = cc >> 6, d = cc & 63;
#pragma unroll
      for (int j = 0; j < 4; ++j) {
        int row = mb + wr + m * 16 + (lane >> 4) * 4 + j;
        int bidx = row >> 11, s = row & 2047;
        float val = acc[m][n][j] + bv;
        if (type == 0)
          qb[(((size_t)(bidx * 16 + h)) * 2048 + s) * 64 + d] = f2bf(val * SCALEQ);
        else if (type == 1)
          kb[(((size_t)(bidx * 16 + h)) * 2048 + s) * 64 + d] = f2bf(val);
        else
          vtb[(((size_t)(bidx * 16 + h)) * 64 + d) * 2048 + s] = f2bf(val);
      }
    }
}

// ---------------- flash attention: 32x32 MFMA, in-register softmax ----------------
// vs round 4 (passing): (1) f2bf pack -> cvt_pk_bf16 (same verified shfl/select
// placement), (2) no barrier (independent waves), (3) TWO 32-q streams per wave
// sharing K/V fragments (2x load amortization + ILP). grid (8,64), 2 waves/SIMD.
__global__ __launch_bounds__(256, 2) void attn_kernel(const unsigned short* __restrict__ qg,
                                                      const unsigned short* __restrict__ kgl,
                                                      const unsigned short* __restrict__ vtg,
                                                      unsigned short* __restrict__ attnb) {
  const int tid = threadIdx.x;
  const int lane = tid & 63;
  const int l31 = lane & 31, hl = lane >> 5;
  const int h8 = hl * 8;
  const int wave = tid >> 6;

  // XCD-locality remap: 8 bh per XCD (K+V of 8 bh = 4MB = one XCD L2)
  const int L = blockIdx.y * 8 + blockIdx.x;  // 0..511
  const int xcd = L & 7, sl = L >> 3;
  const int bh = xcd * 8 + (sl & 7);
  const int qt = sl >> 3;  // 0..7
  const int b = bh >> 4, hh = bh & 15;

  const unsigned short* Qg = qg + (size_t)bh * 2048 * 64;
  const unsigned short* Kg = kgl + (size_t)bh * 2048 * 64;
  const unsigned short* Vg = vtg + (size_t)bh * 64 * 2048;
  const int q0 = qt * 256 + wave * 64;

  // persistent Q B-frags for both streams: col q = q0 + s2*32 + l31
  bf16x8 qf[2][4];
#pragma unroll
  for (int s2 = 0; s2 < 2; ++s2)
#pragma unroll
    for (int dw = 0; dw < 4; ++dw)
      qf[s2][dw] = *(const bf16x8*)&Qg[(size_t)(q0 + s2 * 32 + l31) * 64 + dw * 16 + h8];

  f32x16 o0[2] = {{0.f}, {0.f}};
  f32x16 o1[2] = {{0.f}, {0.f}};
  float mrun[2] = {-1e30f, -1e30f};
  float lrun[2] = {0.f, 0.f};

  const bool h = (hl != 0);
  union PU { uint32_t u[4]; bf16x8 v; };

  for (int kbase = 0; kbase < 2048; kbase += 32) {
    // K A-frags: row key = kbase + l31, d = dw*16 + h8 (shared by both streams)
    const unsigned short* kr = &Kg[(size_t)(kbase + l31) * 64 + h8];
    bf16x8 k0 = *(const bf16x8*)&kr[0];
    bf16x8 k1 = *(const bf16x8*)&kr[16];
    bf16x8 k2 = *(const bf16x8*)&kr[32];
    bf16x8 k3 = *(const bf16x8*)&kr[48];
    // V^T A-frags (shared)
    const unsigned short* vr0 = &Vg[(size_t)l31 * 2048 + kbase + h8];
    const unsigned short* vr1 = &Vg[(size_t)(32 + l31) * 2048 + kbase + h8];
    bf16x8 v00 = *(const bf16x8*)&vr0[0];
    bf16x8 v01 = *(const bf16x8*)&vr0[16];
    bf16x8 v10 = *(const bf16x8*)&vr1[0];
    bf16x8 v11 = *(const bf16x8*)&vr1[16];

#pragma unroll
    for (int s2 = 0; s2 < 2; ++s2) {
      // S^T: lane holds 16 key-values for q = q0 + s2*32 + l31
      // sa[r] = S[key = kbase + (r&3) + 8*(r>>2) + 4*hl][q]
      f32x16 sa = {};
      sa = mfma32(k0, qf[s2][0], sa);
      sa = mfma32(k1, qf[s2][1], sa);
      sa = mfma32(k2, qf[s2][2], sa);
      sa = mfma32(k3, qf[s2][3], sa);

      // ---- online softmax, per-lane ----
      float ma = fmaxf(fmaxf(fmaxf(sa[0], sa[1]), fmaxf(sa[2], sa[3])),
                       fmaxf(fmaxf(sa[4], sa[5]), fmaxf(sa[6], sa[7])));
      float mb2 = fmaxf(fmaxf(fmaxf(sa[8], sa[9]), fmaxf(sa[10], sa[11])),
                        fmaxf(fmaxf(sa[12], sa[13]), fmaxf(sa[14], sa[15])));
      float mx = fmaxf(ma, mb2);
      mx = fmaxf(mx, __shfl_xor(mx, 32));  // cross-half (verified primitive)
      // T13 defer-rescale (exp2 domain, p <= 2^6)
      if (!__all(mx <= mrun[s2] + 6.0f)) {
        float nm = fmaxf(mrun[s2], mx);
        float fs = __builtin_amdgcn_exp2f(mrun[s2] - nm);
        mrun[s2] = nm;
        lrun[s2] *= fs;
#pragma unroll
        for (int r = 0; r < 16; ++r) { o0[s2][r] *= fs; o1[s2][r] *= fs; }
      }
#pragma unroll
      for (int r = 0; r < 16; ++r) sa[r] = __builtin_amdgcn_exp2f(sa[r] - mrun[s2]);
      float r0s = ((sa[0] + sa[1]) + (sa[2] + sa[3])) + ((sa[4] + sa[5]) + (sa[6] + sa[7]));
      float r1s = ((sa[8] + sa[9]) + (sa[10] + sa[11])) + ((sa[12] + sa[13]) + (sa[14] + sa[15]));
      float rs = r0s + r1s;
      rs += __shfl_xor(rs, 32);  // cross-half
      lrun[s2] += rs;

      // ---- P -> PV B-frags: cvt_pk pack + verified shfl_xor(32)+select placement ----
      //   c0=(0,1)/(4,5) c1=(2,3)/(6,7) c2=(8,9)/(12,13) c3=(10,11)/(14,15)  [hl0/hl1]
      uint32_t c0 = cvtpk(sa[0], sa[1]);
      uint32_t c1 = cvtpk(sa[2], sa[3]);
      uint32_t c2 = cvtpk(sa[4], sa[5]);
      uint32_t c3 = cvtpk(sa[6], sa[7]);
      uint32_t c4 = cvtpk(sa[8], sa[9]);
      uint32_t c5 = cvtpk(sa[10], sa[11]);
      uint32_t c6 = cvtpk(sa[12], sa[13]);
      uint32_t c7 = cvtpk(sa[14], sa[15]);
      uint32_t x0 = (uint32_t)__shfl_xor((int)c0, 32);
      uint32_t x1 = (uint32_t)__shfl_xor((int)c1, 32);
      uint32_t x2 = (uint32_t)__shfl_xor((int)c2, 32);
      uint32_t x3 = (uint32_t)__shfl_xor((int)c3, 32);
      uint32_t x4 = (uint32_t)__shfl_xor((int)c4, 32);
      uint32_t x5 = (uint32_t)__shfl_xor((int)c5, 32);
      uint32_t x6 = (uint32_t)__shfl_xor((int)c6, 32);
      uint32_t x7 = (uint32_t)__shfl_xor((int)c7, 32);
      PU p0, p1;
      // B-frag: lane dwords hold keys (hl*8 + {0,1},{2,3},{4,5},{6,7}) per 16-chunk
      p0.u[0] = h ? x2 : c0;  p0.u[1] = h ? x3 : c1;
      p0.u[2] = h ? c2 : x0;  p0.u[3] = h ? c3 : x1;   // keys 0..15
      p1.u[0] = h ? x6 : c4;  p1.u[1] = h ? x7 : c5;
      p1.u[2] = h ? c6 : x4;  p1.u[3] = h ? c7 : x5;   // keys 16..31

      // ---- O^T += V^T x P^T ----
      o0[s2] = mfma32(v00, p0.v, o0[s2]);
      o0[s2] = mfma32(v01, p1.v, o0[s2]);
      o1[s2] = mfma32(v10, p0.v, o1[s2]);
      o1[s2] = mfma32(v11, p1.v, o1[s2]);
    }
  }

  // ---- epilogue: per-lane normalize (q = q0 + s2*32 + l31), store O^T ----
#pragma unroll
  for (int s2 = 0; s2 < 2; ++s2) {
    float invl = 1.0f / lrun[s2];
    const size_t base = ((size_t)(b * 2048 + q0 + s2 * 32 + l31)) * 1024 + hh * 64;
#pragma unroll
    for (int r = 0; r < 16; ++r) {
      int d = (r & 3) + 8 * (r >> 2) + 4 * hl;
      attnb[base + d] = f2bf(o0[s2][r] * invl);
      attnb[base + 32 + d] = f2bf(o1[s2][r] * invl);
    }
  }
}

// ---------------- proj GEMM: attn[8192,1024] x [1024,1024] + bias -> fp32 out ----------------
__global__ __launch_bounds__(256) void proj_gemm(const unsigned short* __restrict__ abf,
                                                 const unsigned short* __restrict__ wT,
                                                 const float* __restrict__ bias,
                                                 float* __restrict__ outp) {
  __shared__ unsigned short As[128 * 32];
  __shared__ unsigned short Bs[128 * 32];
  const int tid = threadIdx.x, lane = tid & 63, wave = tid >> 6;
  const int mb = blockIdx.y * 128, nb = blockIdx.x * 128;
  const int wr = (wave >> 1) * 64, wc = (wave & 1) * 64;
  const int fr = lane & 15, fk = (lane >> 4) * 8;
  f32x4 acc[4][4] = {};
  for (int kt = 0; kt < 1024; kt += 32) {
    __syncthreads();
#pragma unroll
    for (int i = 0; i < 2; ++i) {
      int ch = wave * 128 + i * 64 + lane;
      int r = ch >> 2, ko = (ch & 3) * 8;
      gload_lds16(abf + (size_t)(mb + r) * 1024 + kt + ko, &As[(wave * 128 + i * 64) * 8]);
      gload_lds16(wT + (size_t)(nb + r) * 1024 + kt + ko, &Bs[(wave * 128 + i * 64) * 8]);
    }
    __syncthreads();
    bf16x8 a[4], bq[4];
#pragma unroll
    for (int m = 0; m < 4; ++m) a[m] = *(const bf16x8*)&As[(wr + m * 16 + fr) * 32 + fk];
#pragma unroll
    for (int n = 0; n < 4; ++n) bq[n] = *(const bf16x8*)&Bs[(wc + n * 16 + fr) * 32 + fk];
#pragma unroll
    for (int m = 0; m < 4; ++m)
#pragma unroll
      for (int n = 0; n < 4; ++n) acc[m][n] = mfma16(a[m], bq[n], acc[m][n]);
  }
#pragma unroll
  for (int m = 0; m < 4; ++m)
#pragma unroll
    for (int n = 0; n < 4; ++n) {
      int col = nb + wc + n * 16 + fr;
      float bv = bias[col];
#pragma unroll
      for (int j = 0; j < 4; ++j) {
        int row = mb + wr + m * 16 + (lane >> 4) * 4 + j;
        outp[(size_t)row * 1024 + col] = acc[m][n][j] + bv;
      }
    }
}

extern "C" void kernel_launch(void* const* d_in, const int* in_sizes, int n_in,
                              void* d_out, int out_size, void* d_ws, size_t ws_size,
                              hipStream_t stream) {
  const float* x = (const float*)d_in[0];
  const float* w_qkv = (const float*)d_in[1];
  const float* b_qkv = (const float*)d_in[2];
  const float* w_proj = (const float*)d_in[3];
  const float* b_proj = (const float*)d_in[4];
  float* outp = (float*)d_out;
  char* ws = (char*)d_ws;

  const size_t OFF_XBF = 0;                 // 16,777,216 (also reused as attn output)
  const size_t OFF_WTQKV = 16777216;        //  6,291,456
  const size_t OFF_WTPROJ = 23068672;       //  2,097,152
  const size_t OFF_Q = 25165824;            // 16,777,216
  const size_t OFF_K = 41943040;            // 16,777,216
  const size_t OFF_VT = 58720256;           // 16,777,216
  const size_t NEED = 75497472;
  if (ws_size < NEED) return;

  unsigned short* xbf = (unsigned short*)(ws + OFF_XBF);
  unsigned short* wTqkv = (unsigned short*)(ws + OFF_WTQKV);
  unsigned short* wTproj = (unsigned short*)(ws + OFF_WTPROJ);
  unsigned short* qbuf = (unsigned short*)(ws + OFF_Q);
  unsigned short* kbuf = (unsigned short*)(ws + OFF_K);
  unsigned short* vtbuf = (unsigned short*)(ws + OFF_VT);
  unsigned short* attnb = xbf;  // alias: xbf dead after qkv_gemm

  hipLaunchKernelGGL(convert_f32_bf16, dim3(4096), dim3(256), 0, stream, x, xbf);
  hipLaunchKernelGGL(transpose_to_bf16, dim3(48, 16), dim3(256), 0, stream, w_qkv, wTqkv, 1024, 3072);
  hipLaunchKernelGGL(transpose_to_bf16, dim3(16, 16), dim3(256), 0, stream, w_proj, wTproj, 1024, 1024);
  hipLaunchKernelGGL(qkv_gemm, dim3(24, 64), dim3(256), 0, stream, xbf, wTqkv, b_qkv, qbuf, kbuf, vtbuf);
  hipLaunchKernelGGL(attn_kernel, dim3(8, 64), dim3(256), 0, stream, qbuf, kbuf, vtbuf, attnb);
  hipLaunchKernelGGL(proj_gemm, dim3(8, 64), dim3(256), 0, stream, attnb, wTproj, b_proj, outp);
}